// Round 12
// baseline (58.697 us; speedup 1.0000x reference)
//
#include <hip/hip_runtime.h>

// DkNN p-value: total = sum_k nc[b,k,l]; p = (C - count(cali < total)) / C.
//
// Single fused dispatch, grid 256 x 1024 (1 block/CU, R8 optimum). Per block:
//   0. PREFETCH pipeline stages: issue iterations 0,1's loads (16x float4,
//      clamped idx, sched_barrier-pinned)
//   1. zero 8192-bin LDS hist
//   2. hist: full cali pass (400 KB, L2-resident) via LDS atomicAdd
//   3. barrier; shfl block-scan -> per-bin midpoint table in place; barrier
//   4. STEADY PIPELINED STREAM: register double-buffer, 1-ahead:
//        consume A(i) -> refill A(i+2) -> consume B(i+1) -> refill B(i+3)
//      in-order vmcnt leaves the other buffer's 8 loads in flight during each
//      consume (no full drain per iteration).
//   L templated (=1000): b = flat/L becomes a magic-multiply.
// R-ledger: fused per-block hist=64.5; multi-dispatch=73.5; wave-special=75.4;
// grid-barrier=196.8; hidden-prologue 16w=60.4; 32w depth1=61.2 (equal bytes
// in flight -> latency-limited, not occupancy-limited; hence this pipeline).
// Binning: monotone uniform over [-8,8), width 2^-9; mid-count error <=
// peak-bin/2 ~= 3.9e-4 vs 2e-2 threshold. Integer hist order-independent ->
// deterministic. Regular stores (known-good). d_ws unused.

#define NBINS 8192
#define BIN_LO 8.0f
#define BIN_SCALE 512.0f /* NBINS / 16 */
#define BLOCK 1024

__device__ __forceinline__ int bin_of(float c) {
    float t = (c + BIN_LO) * BIN_SCALE;
    t = fminf(t, (float)(NBINS - 1));
    t = fmaxf(t, 0.0f);
    return (int)t; // monotone in c
}

// In-place: mid[] holds raw histogram on entry, per-bin midpoints on exit.
// All 1024 threads; each owns 8 consecutive bins. 2 internal barriers.
__device__ __forceinline__ void scan_mid(int* mid, int* wsum) {
    const int t = threadIdx.x;
    const int lane = t & 63;
    const int wid = t >> 6;
    const int base = t * 8;
    int h[8];
    int sum = 0;
    #pragma unroll
    for (int i = 0; i < 8; ++i) { h[i] = mid[base + i]; sum += h[i]; }
    int inc = sum;
    #pragma unroll
    for (int off = 1; off < 64; off <<= 1) {
        int v = __shfl_up(inc, off);
        if (lane >= off) inc += v;
    }
    if (lane == 63) wsum[wid] = inc;
    __syncthreads();
    if (wid == 0) {
        int w = (lane < 16) ? wsum[lane] : 0;
        int winc = w;
        #pragma unroll
        for (int off = 1; off < 16; off <<= 1) {
            int v = __shfl_up(winc, off);
            if (lane >= off) winc += v;
        }
        if (lane < 16) wsum[lane] = winc - w;
    }
    __syncthreads();
    int run = wsum[wid] + (inc - sum);
    #pragma unroll
    for (int i = 0; i < 8; ++i) {
        mid[base + i] = (2 * run + h[i]) >> 1; // (cdf[j]+cdf[j+1])/2
        run += h[i];
    }
}

struct Buf { float4 v[8]; };

__device__ __forceinline__ void load8(Buf& bf, const float* __restrict__ p, int L) {
    #pragma unroll
    for (int k = 0; k < 8; ++k)
        bf.v[k] = *reinterpret_cast<const float4*>(p + k * L);
}

__device__ __forceinline__ void fold8(const Buf& bf, float s[4]) {
    s[0] = ((bf.v[0].x + bf.v[1].x) + (bf.v[2].x + bf.v[3].x)) +
           ((bf.v[4].x + bf.v[5].x) + (bf.v[6].x + bf.v[7].x));
    s[1] = ((bf.v[0].y + bf.v[1].y) + (bf.v[2].y + bf.v[3].y)) +
           ((bf.v[4].y + bf.v[5].y) + (bf.v[6].y + bf.v[7].y));
    s[2] = ((bf.v[0].z + bf.v[1].z) + (bf.v[2].z + bf.v[3].z)) +
           ((bf.v[4].z + bf.v[5].z) + (bf.v[6].z + bf.v[7].z));
    s[3] = ((bf.v[0].w + bf.v[1].w) + (bf.v[2].w + bf.v[3].w)) +
           ((bf.v[4].w + bf.v[5].w) + (bf.v[6].w + bf.v[7].w));
}

__device__ __forceinline__ void lookup_store(const int* mid, const float s[4],
                                             float* __restrict__ out, int idx,
                                             int C, float invC) {
    float4 p;
    p.x = (float)(C - mid[bin_of(s[0])]) * invC;
    p.y = (float)(C - mid[bin_of(s[1])]) * invC;
    p.z = (float)(C - mid[bin_of(s[2])]) * invC;
    p.w = (float)(C - mid[bin_of(s[3])]) * invC;
    *reinterpret_cast<float4*>(out + (idx << 2)) = p;
}

// LT > 0: compile-time L (division -> magic mul). LT == 0: runtime L.
template <int LT>
__global__ __launch_bounds__(BLOCK, 4) void dknn_k8_pipe_kernel(
        const float* __restrict__ nc, const float* __restrict__ cali,
        float* __restrict__ out, int n4, int Lrt, int C, float invC) {
    const int L = (LT > 0) ? LT : Lrt;
    const int L7 = 7 * L;
    __shared__ int mid[NBINS];
    __shared__ int wsum[16];
    const int t = threadIdx.x;
    const int gid = blockIdx.x * BLOCK + t;
    const int nth = gridDim.x * BLOCK;

    // row base for vec4-output unit idx: flat = idx*4; addr = flat + (flat/L)*7L
    auto rb = [&](int idx) -> const float* {
        int flat = idx << 2;
        int b = flat / L;
        return nc + (size_t)((unsigned)flat + (unsigned)b * (unsigned)L7);
    };

    // 0. prologue prefetch: pipeline stages 0 and 1 (clamped, branchless)
    int iA = gid;
    int iB = gid + nth;
    Buf A, B;
    load8(A, rb(min(iA, n4 - 1)), L);
    load8(B, rb(min(iB, n4 - 1)), L);
    __builtin_amdgcn_sched_barrier(0); // pin: loads issued before hist

    // 1. zero hist (8 ints/thread, stride-1024, conflict-free)
    #pragma unroll
    for (int i = 0; i < NBINS / BLOCK; ++i) mid[t + i * BLOCK] = 0;
    __syncthreads();

    // 2. hist: full cali pass, LDS atomics
    {
        const int nvec = C >> 2;
        const float4* cali4 = (const float4*)cali;
        for (int i = t; i < nvec; i += BLOCK) {
            float4 v = cali4[i];
            atomicAdd(&mid[bin_of(v.x)], 1);
            atomicAdd(&mid[bin_of(v.y)], 1);
            atomicAdd(&mid[bin_of(v.z)], 1);
            atomicAdd(&mid[bin_of(v.w)], 1);
        }
        for (int i = (nvec << 2) + t; i < C; i += BLOCK)
            atomicAdd(&mid[bin_of(cali[i])], 1);
    }

    // 3. table
    __syncthreads();
    scan_mid(mid, wsum);
    __syncthreads();

    // 4. steady pipelined stream: consume A, refill A(i+2); consume B, refill B(i+3)
    while (iA < n4) {
        float s[4];
        fold8(A, s);
        lookup_store(mid, s, out, iA, C, invC);
        int iN = iB + nth; // next index for buffer A
        load8(A, rb(min(iN, n4 - 1)), L);
        if (iB < n4) {
            float r[4];
            fold8(B, r);
            lookup_store(mid, r, out, iB, C, invC);
        }
        int iM = iN + nth; // next index for buffer B
        load8(B, rb(min(iM, n4 - 1)), L);
        iA = iN;
        iB = iM;
    }
}

// Generic fallback (any K, any L): per-block hist, uniform roles.
__global__ __launch_bounds__(BLOCK, 4) void dknn_generic_kernel(
        const float* __restrict__ nc, const float* __restrict__ cali,
        float* __restrict__ out, int BL, int K, int L, int C, float invC) {
    __shared__ int mid[NBINS];
    __shared__ int wsum[16];
    const int t = threadIdx.x;
    #pragma unroll
    for (int i = 0; i < NBINS / BLOCK; ++i) mid[t + i * BLOCK] = 0;
    __syncthreads();
    for (int i = t; i < C; i += BLOCK) atomicAdd(&mid[bin_of(cali[i])], 1);
    __syncthreads();
    scan_mid(mid, wsum);
    __syncthreads();
    const int stride = gridDim.x * BLOCK;
    for (int i = blockIdx.x * BLOCK + t; i < BL; i += stride) {
        int b = i / L;
        int l = i - b * L;
        const float* base = nc + (size_t)b * (size_t)K * (size_t)L + l;
        float s = 0.f;
        for (int k = 0; k < K; ++k) s += base[(size_t)k * L];
        out[i] = (float)(C - mid[bin_of(s)]) * invC;
    }
}

extern "C" void kernel_launch(void* const* d_in, const int* in_sizes, int n_in,
                              void* d_out, int out_size, void* d_ws, size_t ws_size,
                              hipStream_t stream) {
    const float* nc   = (const float*)d_in[0];
    // d_in[1] = label_sample (unused; only defines L)
    const float* cali = (const float*)d_in[2];

    const int L  = in_sizes[1];
    const int C  = in_sizes[2];
    const int BL = out_size;         // B * L
    const int K  = in_sizes[0] / BL; // 8
    const float invC = 1.0f / (float)C;
    float* out = (float*)d_out;

    if ((L & 3) == 0 && K == 8 && BL >= 4) {
        int n4 = BL >> 2;
        int nblocks = 256; // 1 block/CU (R8 optimum)
        int needed = (n4 + BLOCK - 1) / BLOCK;
        if (nblocks > needed) nblocks = needed;
        if (L == 1000) {
            dknn_k8_pipe_kernel<1000><<<nblocks, BLOCK, 0, stream>>>(
                nc, cali, out, n4, L, C, invC);
        } else {
            dknn_k8_pipe_kernel<0><<<nblocks, BLOCK, 0, stream>>>(
                nc, cali, out, n4, L, C, invC);
        }
    } else {
        int nblocks = 512;
        int needed = (BL + BLOCK - 1) / BLOCK;
        if (nblocks > needed) nblocks = needed;
        dknn_generic_kernel<<<nblocks, BLOCK, 0, stream>>>(
            nc, cali, out, BL, K, L, C, invC);
    }
}

// Round 13
// 57.535 us; speedup vs baseline: 1.0202x; 1.0202x over previous
//
#include <hip/hip_runtime.h>

// DkNN p-value: total = sum_k nc[b,k,l]; p = (C - count(cali < total)) / C.
//
// Single fused dispatch, grid 256 x 1024 (1 block/CU). Per block:
//   0. PREFETCH: issue iterations 0,1's loads (16x float4, clamped idx,
//      sched_barrier-pinned)
//   1. zero 8192-bin LDS hist
//   2. hist: full cali pass (400 KB, L2/L3-resident) via LDS atomicAdd
//      (hidden under prefetch delivery)
//   3. barrier; shfl block-scan -> LDS table now holds float p-value per bin:
//      pval[j] = (C - (cdf[j]+cdf[j+1])/2) * invC  (lookup = 1 ds_read, no
//      int->float math on the stream's critical path)
//   4. steady pipelined stream (register double-buffer, 1-ahead) with
//      NONTEMPORAL stores: out (33 MB/replay) must not evict nc from L3 --
//      nc is 262 MB vs 256 MB L3; R2's FETCH=140MB showed ~half resident.
//      nt-store is the single variable vs R12 (58.7 us); it was never
//      isolated before (R5 bundled it with the multi-dispatch regression).
// Binning: monotone uniform over [-8,8), width 2^-9; midpoint error <=
// peak-bin/2 ~= 3.9e-4 vs 2e-2 threshold. Integer hist order-independent ->
// deterministic. L templated (=1000) -> division by magic-multiply. d_ws unused.

#define NBINS 8192
#define BIN_LO 8.0f
#define BIN_SCALE 512.0f /* NBINS / 16 */
#define BLOCK 1024

typedef float floatx4 __attribute__((ext_vector_type(4)));

__device__ __forceinline__ int bin_of(float c) {
    float t = (c + BIN_LO) * BIN_SCALE;
    t = fminf(t, (float)(NBINS - 1));
    t = fmaxf(t, 0.0f);
    return (int)t; // monotone in c
}

// In-place: tbl[] holds raw int histogram on entry (as int bits), float
// p-value per bin on exit. Each thread owns 8 consecutive bins (disjoint
// read/write). 2 internal barriers.
__device__ __forceinline__ void scan_pval(int* tbl, int* wsum, int C, float invC) {
    const int t = threadIdx.x;
    const int lane = t & 63;
    const int wid = t >> 6;
    const int base = t * 8;
    float* ftbl = (float*)tbl;
    int h[8];
    int sum = 0;
    #pragma unroll
    for (int i = 0; i < 8; ++i) { h[i] = tbl[base + i]; sum += h[i]; }
    int inc = sum;
    #pragma unroll
    for (int off = 1; off < 64; off <<= 1) {
        int v = __shfl_up(inc, off);
        if (lane >= off) inc += v;
    }
    if (lane == 63) wsum[wid] = inc;
    __syncthreads();
    if (wid == 0) {
        int w = (lane < 16) ? wsum[lane] : 0;
        int winc = w;
        #pragma unroll
        for (int off = 1; off < 16; off <<= 1) {
            int v = __shfl_up(winc, off);
            if (lane >= off) winc += v;
        }
        if (lane < 16) wsum[lane] = winc - w;
    }
    __syncthreads();
    int run = wsum[wid] + (inc - sum);
    #pragma unroll
    for (int i = 0; i < 8; ++i) {
        int midc = (2 * run + h[i]) >> 1;            // (cdf[j]+cdf[j+1])/2
        ftbl[base + i] = (float)(C - midc) * invC;   // p-value for this bin
        run += h[i];
    }
}

struct Buf { float4 v[8]; };

__device__ __forceinline__ void load8(Buf& bf, const float* __restrict__ p, int L) {
    #pragma unroll
    for (int k = 0; k < 8; ++k)
        bf.v[k] = *reinterpret_cast<const float4*>(p + k * L);
}

__device__ __forceinline__ void fold8(const Buf& bf, float s[4]) {
    s[0] = ((bf.v[0].x + bf.v[1].x) + (bf.v[2].x + bf.v[3].x)) +
           ((bf.v[4].x + bf.v[5].x) + (bf.v[6].x + bf.v[7].x));
    s[1] = ((bf.v[0].y + bf.v[1].y) + (bf.v[2].y + bf.v[3].y)) +
           ((bf.v[4].y + bf.v[5].y) + (bf.v[6].y + bf.v[7].y));
    s[2] = ((bf.v[0].z + bf.v[1].z) + (bf.v[2].z + bf.v[3].z)) +
           ((bf.v[4].z + bf.v[5].z) + (bf.v[6].z + bf.v[7].z));
    s[3] = ((bf.v[0].w + bf.v[1].w) + (bf.v[2].w + bf.v[3].w)) +
           ((bf.v[4].w + bf.v[5].w) + (bf.v[6].w + bf.v[7].w));
}

__device__ __forceinline__ void lookup_store_nt(const float* ftbl, const float s[4],
                                                float* __restrict__ out, int idx) {
    floatx4 p;
    p.x = ftbl[bin_of(s[0])];
    p.y = ftbl[bin_of(s[1])];
    p.z = ftbl[bin_of(s[2])];
    p.w = ftbl[bin_of(s[3])];
    __builtin_nontemporal_store(p, reinterpret_cast<floatx4*>(out + (idx << 2)));
}

// LT > 0: compile-time L (division -> magic mul). LT == 0: runtime L.
template <int LT>
__global__ __launch_bounds__(BLOCK, 4) void dknn_k8_pipent_kernel(
        const float* __restrict__ nc, const float* __restrict__ cali,
        float* __restrict__ out, int n4, int Lrt, int C, float invC) {
    const int L = (LT > 0) ? LT : Lrt;
    const int L7 = 7 * L;
    __shared__ int tbl[NBINS];
    __shared__ int wsum[16];
    const float* ftbl = (const float*)tbl;
    const int t = threadIdx.x;
    const int gid = blockIdx.x * BLOCK + t;
    const int nth = gridDim.x * BLOCK;

    // row base for vec4-output unit idx: flat = idx*4; addr = flat + (flat/L)*7L
    auto rb = [&](int idx) -> const float* {
        int flat = idx << 2;
        int b = flat / L;
        return nc + (size_t)((unsigned)flat + (unsigned)b * (unsigned)L7);
    };

    // 0. prologue prefetch: pipeline stages 0 and 1 (clamped, branchless)
    int iA = gid;
    int iB = gid + nth;
    Buf A, B;
    load8(A, rb(min(iA, n4 - 1)), L);
    load8(B, rb(min(iB, n4 - 1)), L);
    __builtin_amdgcn_sched_barrier(0); // pin: loads issued before hist

    // 1. zero hist (8 ints/thread, stride-1024, conflict-free)
    #pragma unroll
    for (int i = 0; i < NBINS / BLOCK; ++i) tbl[t + i * BLOCK] = 0;
    __syncthreads();

    // 2. hist: full cali pass, LDS atomics
    {
        const int nvec = C >> 2;
        const float4* cali4 = (const float4*)cali;
        for (int i = t; i < nvec; i += BLOCK) {
            float4 v = cali4[i];
            atomicAdd(&tbl[bin_of(v.x)], 1);
            atomicAdd(&tbl[bin_of(v.y)], 1);
            atomicAdd(&tbl[bin_of(v.z)], 1);
            atomicAdd(&tbl[bin_of(v.w)], 1);
        }
        for (int i = (nvec << 2) + t; i < C; i += BLOCK)
            atomicAdd(&tbl[bin_of(cali[i])], 1);
    }

    // 3. table: hist -> float p-value per bin (in place)
    __syncthreads();
    scan_pval(tbl, wsum, C, invC);
    __syncthreads();

    // 4. steady pipelined stream: consume A, refill A(i+2); consume B, refill B(i+3)
    while (iA < n4) {
        float s[4];
        fold8(A, s);
        lookup_store_nt(ftbl, s, out, iA);
        int iN = iB + nth; // next index for buffer A
        load8(A, rb(min(iN, n4 - 1)), L);
        if (iB < n4) {
            float r[4];
            fold8(B, r);
            lookup_store_nt(ftbl, r, out, iB);
        }
        int iM = iN + nth; // next index for buffer B
        load8(B, rb(min(iM, n4 - 1)), L);
        iA = iN;
        iB = iM;
    }
}

// Generic fallback (any K, any L): per-block hist, uniform roles.
__global__ __launch_bounds__(BLOCK, 4) void dknn_generic_kernel(
        const float* __restrict__ nc, const float* __restrict__ cali,
        float* __restrict__ out, int BL, int K, int L, int C, float invC) {
    __shared__ int tbl[NBINS];
    __shared__ int wsum[16];
    const float* ftbl = (const float*)tbl;
    const int t = threadIdx.x;
    #pragma unroll
    for (int i = 0; i < NBINS / BLOCK; ++i) tbl[t + i * BLOCK] = 0;
    __syncthreads();
    for (int i = t; i < C; i += BLOCK) atomicAdd(&tbl[bin_of(cali[i])], 1);
    __syncthreads();
    scan_pval(tbl, wsum, C, invC);
    __syncthreads();
    const int stride = gridDim.x * BLOCK;
    for (int i = blockIdx.x * BLOCK + t; i < BL; i += stride) {
        int b = i / L;
        int l = i - b * L;
        const float* base = nc + (size_t)b * (size_t)K * (size_t)L + l;
        float s = 0.f;
        for (int k = 0; k < K; ++k) s += base[(size_t)k * L];
        out[i] = ftbl[bin_of(s)];
    }
}

extern "C" void kernel_launch(void* const* d_in, const int* in_sizes, int n_in,
                              void* d_out, int out_size, void* d_ws, size_t ws_size,
                              hipStream_t stream) {
    const float* nc   = (const float*)d_in[0];
    // d_in[1] = label_sample (unused; only defines L)
    const float* cali = (const float*)d_in[2];

    const int L  = in_sizes[1];
    const int C  = in_sizes[2];
    const int BL = out_size;         // B * L
    const int K  = in_sizes[0] / BL; // 8
    const float invC = 1.0f / (float)C;
    float* out = (float*)d_out;

    if ((L & 3) == 0 && K == 8 && BL >= 4) {
        int n4 = BL >> 2;
        int nblocks = 256; // 1 block/CU
        int needed = (n4 + BLOCK - 1) / BLOCK;
        if (nblocks > needed) nblocks = needed;
        if (L == 1000) {
            dknn_k8_pipent_kernel<1000><<<nblocks, BLOCK, 0, stream>>>(
                nc, cali, out, n4, L, C, invC);
        } else {
            dknn_k8_pipent_kernel<0><<<nblocks, BLOCK, 0, stream>>>(
                nc, cali, out, n4, L, C, invC);
        }
    } else {
        int nblocks = 512;
        int needed = (BL + BLOCK - 1) / BLOCK;
        if (nblocks > needed) nblocks = needed;
        dknn_generic_kernel<<<nblocks, BLOCK, 0, stream>>>(
            nc, cali, out, BL, K, L, C, invC);
    }
}